// Round 13
// baseline (265.709 us; speedup 1.0000x reference)
//
#include <hip/hip_runtime.h>
#include <math.h>

// Gumbel subset (relaxed top-k) — B=2048 rows, N=8192, K=64 softmax steps.
// Multiplicative reformulation: v_i = exp(s0_i - M0), per step:
//   w = v*rinv(S); kh += w; v = fma(-w, v, v); part' = sum(v).
// R13: R6's proven minimal-f32 skeleton (busy == 67us op floor), with the
// PROLOGUE register diet: s0 staging moved to LDS (7 of 8 chunks, 28.7 KB
// -> 5 blocks/CU; 8th chunk kept in regs to stay under 32 KB) and reg cap
// 102 via __launch_bounds__(256,5). R6's allocation (~160 regs) limited
// occupancy to 3 waves/SIMD -> 39% idle at the per-iteration barrier chain.
// Now ~95 live regs -> 5 waves/SIMD from 5 INDEPENDENT rows per SIMD:
// barrier stalls stagger across blocks and hide under each other's issue.
// (R9-R12 established VOP3P is 2-pass on CDNA4 -> no packing lever; the
// scalar-f32 rate is the ceiling, so idle is the only recoverable term.)

#define BROWS 2048
#define NCOLS 8192
#define KSTEPS 64

#define THREADS 256
#define EPT (NCOLS / THREADS)  // 32 elements per thread
#define NCH (EPT / 4)          // 8 float4 chunks per thread
#define LCH 7                  // chunks staged in LDS (last chunk in regs)
#define NWAVE (THREADS / 64)   // 4

__global__ __launch_bounds__(THREADS, 5) void gumbel_subset_kernel(
    const float* __restrict__ scores,
    const float* __restrict__ g,
    float* __restrict__ out)
{
    const int row = blockIdx.x;
    const int t = threadIdx.x;
    const float* __restrict__ srow = scores + (size_t)row * NCOLS;
    const float* __restrict__ grow = g + (size_t)row * NCOLS;
    float* __restrict__ orow = out + (size_t)row * NCOLS;

    __shared__ float4 s0l[LCH * THREADS];  // 28672 B staging
    __shared__ float red[2][NWAVE];        // 32 B reduce partials

    float v[EPT];
    float kh[EPT];

    // ---- pass 1: s0 = scores + g -> LDS (chunks 0..6) / regs (chunk 7) ----
    float m = -INFINITY;
    float4 c7;
#pragma unroll
    for (int c = 0; c < LCH; ++c) {
        const int idx = c * (THREADS * 4) + t * 4;
        const float4 a = *reinterpret_cast<const float4*>(srow + idx);
        const float4 b = *reinterpret_cast<const float4*>(grow + idx);
        float4 p;
        p.x = a.x + b.x; p.y = a.y + b.y; p.z = a.z + b.z; p.w = a.w + b.w;
        s0l[c * THREADS + t] = p;
        m = fmaxf(m, fmaxf(fmaxf(p.x, p.y), fmaxf(p.z, p.w)));
    }
    {
        const int idx = LCH * (THREADS * 4) + t * 4;
        const float4 a = *reinterpret_cast<const float4*>(srow + idx);
        const float4 b = *reinterpret_cast<const float4*>(grow + idx);
        c7.x = a.x + b.x; c7.y = a.y + b.y; c7.z = a.z + b.z; c7.w = a.w + b.w;
        m = fmaxf(m, fmaxf(fmaxf(c7.x, c7.y), fmaxf(c7.z, c7.w)));
    }

    const int wave = t >> 6;
    const int lane = t & 63;

    // ---- block max reduction (also fences s0l writes->reads) ----
#pragma unroll
    for (int off = 32; off > 0; off >>= 1)
        m = fmaxf(m, __shfl_xor(m, off, 64));
    if (lane == 0) red[0][wave] = m;
    __syncthreads();
    m = fmaxf(fmaxf(red[0][0], red[0][1]), fmaxf(red[0][2], red[0][3]));
    __syncthreads(); // red[0] is re-written by iteration 0 below

    // ---- pass 2: v = exp(s0 - M0), kh = 0, initial partial sums ----
    float sa = 0.0f, sb = 0.0f, sc = 0.0f, sd = 0.0f;
#pragma unroll
    for (int c = 0; c < LCH; ++c) {
        const float4 p = s0l[c * THREADS + t];
        v[c * 4 + 0] = __expf(p.x - m);
        v[c * 4 + 1] = __expf(p.y - m);
        v[c * 4 + 2] = __expf(p.z - m);
        v[c * 4 + 3] = __expf(p.w - m);
        kh[c * 4 + 0] = 0.0f; kh[c * 4 + 1] = 0.0f;
        kh[c * 4 + 2] = 0.0f; kh[c * 4 + 3] = 0.0f;
        sa += v[c * 4 + 0]; sb += v[c * 4 + 1];
        sc += v[c * 4 + 2]; sd += v[c * 4 + 3];
    }
    {
        const int e = LCH * 4;
        v[e + 0] = __expf(c7.x - m);
        v[e + 1] = __expf(c7.y - m);
        v[e + 2] = __expf(c7.z - m);
        v[e + 3] = __expf(c7.w - m);
        kh[e + 0] = 0.0f; kh[e + 1] = 0.0f; kh[e + 2] = 0.0f; kh[e + 3] = 0.0f;
        sa += v[e + 0]; sb += v[e + 1]; sc += v[e + 2]; sd += v[e + 3];
    }

    // ---- K relaxation steps (R6-proven structure, f32, 4 ops/elem) ----
#pragma unroll 2
    for (int it = 0; it < KSTEPS; ++it) {
        float s = (sa + sb) + (sc + sd);
#pragma unroll
        for (int off = 32; off > 0; off >>= 1)
            s += __shfl_xor(s, off, 64);

        const int buf = it & 1;
        if (lane == 0) red[buf][wave] = s;
        __syncthreads();
        const float S = (red[buf][0] + red[buf][1]) + (red[buf][2] + red[buf][3]);
        const float rinv = __builtin_amdgcn_rcpf(S);

        sa = 0.0f; sb = 0.0f; sc = 0.0f; sd = 0.0f;
#pragma unroll
        for (int e = 0; e < EPT; e += 4) {
            const float w0 = v[e + 0] * rinv;
            const float w1 = v[e + 1] * rinv;
            const float w2 = v[e + 2] * rinv;
            const float w3 = v[e + 3] * rinv;
            kh[e + 0] += w0; kh[e + 1] += w1; kh[e + 2] += w2; kh[e + 3] += w3;
            v[e + 0] = __builtin_fmaf(-w0, v[e + 0], v[e + 0]);
            v[e + 1] = __builtin_fmaf(-w1, v[e + 1], v[e + 1]);
            v[e + 2] = __builtin_fmaf(-w2, v[e + 2], v[e + 2]);
            v[e + 3] = __builtin_fmaf(-w3, v[e + 3], v[e + 3]);
            sa += v[e + 0]; sb += v[e + 1]; sc += v[e + 2]; sd += v[e + 3];
        }
        // single barrier per iteration: next write targets the other buffer;
        // this buffer is only re-written after the *next* barrier.
    }

    // ---- store khot (coalesced float4) ----
#pragma unroll
    for (int c = 0; c < EPT / 4; ++c) {
        const int idx = c * (THREADS * 4) + t * 4;
        float4 o;
        o.x = kh[c * 4 + 0];
        o.y = kh[c * 4 + 1];
        o.z = kh[c * 4 + 2];
        o.w = kh[c * 4 + 3];
        *reinterpret_cast<float4*>(orow + idx) = o;
    }
}

extern "C" void kernel_launch(void* const* d_in, const int* in_sizes, int n_in,
                              void* d_out, int out_size, void* d_ws, size_t ws_size,
                              hipStream_t stream) {
    const float* scores = (const float*)d_in[0];
    const float* g = (const float*)d_in[1];
    float* out = (float*)d_out;
    (void)in_sizes; (void)n_in; (void)out_size; (void)d_ws; (void)ws_size;

    gumbel_subset_kernel<<<BROWS, THREADS, 0, stream>>>(scores, g, out);
}

// Round 14
// 101.142 us; speedup vs baseline: 2.6271x; 2.6271x over previous
//
#include <hip/hip_runtime.h>
#include <math.h>

// Gumbel subset (relaxed top-k) — B=2048 rows, N=8192, K=64 softmax steps.
// Multiplicative reformulation: v_i = exp(s0_i - M0), per step:
//   w = v*rinv(S); kh += w; v = fma(-w, v, v); part' = sum(v).
// R14: R6's proven f32 skeleton (busy == 67us op floor, absmax 0.0039) with
// ONE isolated change: the per-iteration 64-lane sum uses DPP (6 VALU ops,
// ~60cy serial) instead of 6 dependent __shfl_xor/ds_bpermute (~300cy).
// R4/R5 audit: the asm-fmac (present in both) was the proven numerics bug;
// DPP was never falsified. Semantics re-derived: row_shr:1/2/4/8 with
// bound_ctrl=1 (invalid->0, harmless for sum) builds row prefix sums;
// row_bcast:15 (mask 0xa) + row_bcast:31 (mask 0xc) fold row sums into
// lane 63; readlane 63 broadcasts the total (masked lanes add old=0).
// R13 lesson: never cap regs below ~160 (scratch spill, 2.4x regression);
// occupancy is state-bound at ~3 waves/SIMD, so only the serial chain in
// the 42us idle is recoverable.

#define BROWS 2048
#define NCOLS 8192
#define KSTEPS 64

#define THREADS 256
#define EPT (NCOLS / THREADS)  // 32
#define NWAVE (THREADS / 64)   // 4

__device__ __forceinline__ float wave_sum_dpp(float x) {
    int t;
    t = __builtin_amdgcn_update_dpp(0, __builtin_bit_cast(int, x), 0x111, 0xf, 0xf, true);  // row_shr:1
    x += __builtin_bit_cast(float, t);
    t = __builtin_amdgcn_update_dpp(0, __builtin_bit_cast(int, x), 0x112, 0xf, 0xf, true);  // row_shr:2
    x += __builtin_bit_cast(float, t);
    t = __builtin_amdgcn_update_dpp(0, __builtin_bit_cast(int, x), 0x114, 0xf, 0xf, true);  // row_shr:4
    x += __builtin_bit_cast(float, t);
    t = __builtin_amdgcn_update_dpp(0, __builtin_bit_cast(int, x), 0x118, 0xf, 0xf, true);  // row_shr:8
    x += __builtin_bit_cast(float, t);
    // lane 15/31/47/63 now hold their 16-lane row sums
    t = __builtin_amdgcn_update_dpp(0, __builtin_bit_cast(int, x), 0x142, 0xa, 0xf, false); // row_bcast:15 -> rows 1,3
    x += __builtin_bit_cast(float, t);
    t = __builtin_amdgcn_update_dpp(0, __builtin_bit_cast(int, x), 0x143, 0xc, 0xf, false); // row_bcast:31 -> rows 2,3
    x += __builtin_bit_cast(float, t);
    // lane 63 holds the full-wave sum; readlane broadcasts it
    return __builtin_bit_cast(float, __builtin_amdgcn_readlane(__builtin_bit_cast(int, x), 63));
}

__global__ __launch_bounds__(THREADS, 2) void gumbel_subset_kernel(
    const float* __restrict__ scores,
    const float* __restrict__ g,
    float* __restrict__ out)
{
    const int row = blockIdx.x;
    const int t = threadIdx.x;
    const float* __restrict__ srow = scores + (size_t)row * NCOLS;
    const float* __restrict__ grow = g + (size_t)row * NCOLS;
    float* __restrict__ orow = out + (size_t)row * NCOLS;

    float v[EPT];
    float kh[EPT];

    // ---- load s0 = scores + g (coalesced float4), track local max ----
    float m = -INFINITY;
#pragma unroll
    for (int c = 0; c < EPT / 4; ++c) {
        const int idx = c * (THREADS * 4) + t * 4;
        const float4 a = *reinterpret_cast<const float4*>(srow + idx);
        const float4 b = *reinterpret_cast<const float4*>(grow + idx);
        const float s0 = a.x + b.x;
        const float s1 = a.y + b.y;
        const float s2 = a.z + b.z;
        const float s3 = a.w + b.w;
        v[c * 4 + 0] = s0;
        v[c * 4 + 1] = s1;
        v[c * 4 + 2] = s2;
        v[c * 4 + 3] = s3;
        m = fmaxf(m, fmaxf(fmaxf(s0, s1), fmaxf(s2, s3)));
    }

    __shared__ float red[2][NWAVE]; // double-buffered per-wave partials
    const int wave = t >> 6;
    const int lane = t & 63;

    // ---- block max reduction (once; shfl path, proven) ----
#pragma unroll
    for (int off = 32; off > 0; off >>= 1)
        m = fmaxf(m, __shfl_xor(m, off, 64));
    if (lane == 0) red[0][wave] = m;
    __syncthreads();
    m = fmaxf(fmaxf(red[0][0], red[0][1]), fmaxf(red[0][2], red[0][3]));
    __syncthreads(); // red[0] is re-written by iteration 0 below

    // ---- v = exp(s0 - M0), khot = 0, initial partial sums ----
    float sa = 0.0f, sb = 0.0f, sc = 0.0f, sd = 0.0f;
#pragma unroll
    for (int e = 0; e < EPT; e += 4) {
        v[e + 0] = __expf(v[e + 0] - m);
        v[e + 1] = __expf(v[e + 1] - m);
        v[e + 2] = __expf(v[e + 2] - m);
        v[e + 3] = __expf(v[e + 3] - m);
        kh[e + 0] = 0.0f; kh[e + 1] = 0.0f; kh[e + 2] = 0.0f; kh[e + 3] = 0.0f;
        sa += v[e + 0]; sb += v[e + 1]; sc += v[e + 2]; sd += v[e + 3];
    }

    // ---- K relaxation steps ----
#pragma unroll 2
    for (int it = 0; it < KSTEPS; ++it) {
        const float s = wave_sum_dpp((sa + sb) + (sc + sd));

        const int buf = it & 1;
        if (lane == 0) red[buf][wave] = s;
        __syncthreads();
        const float S = (red[buf][0] + red[buf][1]) + (red[buf][2] + red[buf][3]);
        const float rinv = __builtin_amdgcn_rcpf(S);

        sa = 0.0f; sb = 0.0f; sc = 0.0f; sd = 0.0f;
#pragma unroll
        for (int e = 0; e < EPT; e += 4) {
            const float w0 = v[e + 0] * rinv;
            const float w1 = v[e + 1] * rinv;
            const float w2 = v[e + 2] * rinv;
            const float w3 = v[e + 3] * rinv;
            kh[e + 0] += w0; kh[e + 1] += w1; kh[e + 2] += w2; kh[e + 3] += w3;
            v[e + 0] = __builtin_fmaf(-w0, v[e + 0], v[e + 0]);
            v[e + 1] = __builtin_fmaf(-w1, v[e + 1], v[e + 1]);
            v[e + 2] = __builtin_fmaf(-w2, v[e + 2], v[e + 2]);
            v[e + 3] = __builtin_fmaf(-w3, v[e + 3], v[e + 3]);
            sa += v[e + 0]; sb += v[e + 1]; sc += v[e + 2]; sd += v[e + 3];
        }
        // single barrier per iteration: next write targets the other buffer;
        // this buffer is only re-written after the *next* barrier.
    }

    // ---- store khot (coalesced float4) ----
#pragma unroll
    for (int c = 0; c < EPT / 4; ++c) {
        const int idx = c * (THREADS * 4) + t * 4;
        float4 o;
        o.x = kh[c * 4 + 0];
        o.y = kh[c * 4 + 1];
        o.z = kh[c * 4 + 2];
        o.w = kh[c * 4 + 3];
        *reinterpret_cast<float4*>(orow + idx) = o;
    }
}

extern "C" void kernel_launch(void* const* d_in, const int* in_sizes, int n_in,
                              void* d_out, int out_size, void* d_ws, size_t ws_size,
                              hipStream_t stream) {
    const float* scores = (const float*)d_in[0];
    const float* g = (const float*)d_in[1];
    float* out = (float*)d_out;
    (void)in_sizes; (void)n_in; (void)out_size; (void)d_ws; (void)ws_size;

    gumbel_subset_kernel<<<BROWS, THREADS, 0, stream>>>(scores, g, out);
}